// Round 1
// baseline (246.045 us; speedup 1.0000x reference)
//
#include <hip/hip_runtime.h>
#include <math.h>

#define BB 32
#define CCH 224
#define TTT 2048
#define BT (BB*TTT)      // 65536
#define CH (BB*CCH)      // 7168
#define KS 13

// ---------------------------------------------------------------------------
// K1: tiled transpose x (B,C,T) -> xT (B,T,C)  +  partial w-dot over 32-ch tiles
// grid (32 t-tiles, 7 c-tiles, 32 b), block 256
// ---------------------------------------------------------------------------
__global__ __launch_bounds__(256) void k1_transpose_dot(
    const float* __restrict__ x, const float* __restrict__ lw,
    float* __restrict__ xT, double* __restrict__ wpart)
{
    __shared__ float sh[32][65];          // [c in tile][t in tile], +1 pad
    const int tt = blockIdx.x;            // t-tile (64 t)
    const int ct = blockIdx.y;            // c-tile (32 c)
    const int b  = blockIdx.z;
    const int t0 = tt * 64, c0 = ct * 32;
    const int j = threadIdx.x & 63;       // t within tile
    const int i = threadIdx.x >> 6;       // 0..3

    for (int cc = i; cc < 32; cc += 4)
        sh[cc][j] = x[(size_t)(b * CCH + c0 + cc) * TTT + t0 + j];
    __syncthreads();

    // partial dot over this c-tile (threads 0..63, one per t) -- deterministic order
    if (threadIdx.x < 64) {
        double acc = 0.0;
        for (int cc = 0; cc < 32; ++cc)
            acc += (double)sh[cc][threadIdx.x] * (double)lw[c0 + cc];
        wpart[(size_t)ct * BT + b * TTT + t0 + threadIdx.x] = acc;
    }

    // transposed store: xT[b][t][c]
    const int ii = threadIdx.x & 31;      // c within tile
    const int jj = threadIdx.x >> 5;      // 0..7
    for (int s = 0; s < 8; ++s) {
        int j2 = jj + 8 * s;
        xT[(size_t)(b * TTT + t0 + j2) * CCH + c0 + ii] = sh[ii][j2];
    }
}

// ---------------------------------------------------------------------------
// K2: w -> normalized Gaussian kernel (f64).  grid 256, block 256 (one thread per (b,t))
// ---------------------------------------------------------------------------
__global__ __launch_bounds__(256) void k2_kern(
    const double* __restrict__ wpart, double* __restrict__ kern)
{
    const int g = blockIdx.x * 256 + threadIdx.x;   // b*T + t
    double s = 0.0;
    for (int ct = 0; ct < 7; ++ct) s += wpart[(size_t)ct * BT + g];

    const double SMIN = 0.4, SMAX = 10.0;
    double w = 0.5 * (SMIN + SMAX) + s * (SMAX - SMIN);
    w = fmin(fmax(w, SMIN), SMAX);

    // norm over linspace(-60,60,130); exactly symmetric endpoints -> 2x half-sum
    const double step = 120.0 / 129.0;
    double norm = 0.0;
    for (int i2 = 65; i2 <= 129; ++i2) {
        double r = (i2 == 129) ? 60.0 : ((double)i2 * step - 60.0);
        double q = r / w;
        norm += exp(-0.5 * q * q);
    }
    norm *= 2.0;

    double e[7];
    for (int d = 0; d < 7; ++d) {
        double q = (double)d / w;
        e[d] = exp(-0.5 * q * q);
    }
    double* kr = kern + (size_t)g * KS;
    for (int k = 0; k < KS; ++k) {
        int d = k - 6; if (d < 0) d = -d;
        kr[k] = e[d] / norm;        // match ref's division by norm
    }
}

// ---------------------------------------------------------------------------
// K3: 13-tap channel conv + I = x - relu(x - x_mean), f64 accumulation.
// block = (b, 4 consecutive t), 256 threads; thread j<56 computes 4 channels.
// writes I in scan layout [t][chain], chain = b*224 + c
// ---------------------------------------------------------------------------
__global__ __launch_bounds__(256) void k3_conv(
    const float* __restrict__ xT, const double* __restrict__ kern,
    double* __restrict__ Ibuf)
{
    __shared__ __align__(16) float sh[4][240];   // padded row: sh[p] = x[c=p-6]
    const int blk = blockIdx.x;                  // 16384 = 32 b * 512 t-groups
    const int b   = blk >> 9;
    const int tg  = blk & 511;
    const int tq  = threadIdx.x >> 6;            // 0..3 (sub-wave / t)
    const int j   = threadIdx.x & 63;
    const int t   = tg * 4 + tq;

    const float* row = xT + (size_t)(b * TTT + t) * CCH;
    #pragma unroll
    for (int m = 0; m < 4; ++m) {
        int p = 4 * j + m;
        if (p < 236) sh[tq][p] = (p >= 6 && p < 230) ? row[p - 6] : 0.0f;
    }
    __syncthreads();

    if (j < 56) {
        const double* kr = kern + (size_t)(b * TTT + t) * KS;
        double kk[13];
        #pragma unroll
        for (int k = 0; k < 13; ++k) kk[k] = kr[k];

        float f[16];                              // sh[4j .. 4j+15], 16B-aligned
        const float4* f4 = (const float4*)&sh[tq][4 * j];
        ((float4*)f)[0] = f4[0]; ((float4*)f)[1] = f4[1];
        ((float4*)f)[2] = f4[2]; ((float4*)f)[3] = f4[3];

        double* dst = Ibuf + (size_t)t * CH + b * CCH + 4 * j;
        #pragma unroll
        for (int m = 0; m < 4; ++m) {
            double acc = 0.0;
            #pragma unroll
            for (int k = 0; k < 13; ++k) acc += (double)f[m + k] * kk[k];
            double xv = (double)f[m + 6];
            double d  = xv - acc;
            dst[m] = xv - (d > 0.0 ? d : 0.0);    // x - relu(x - x_mean)
        }
    }
}

// ---------------------------------------------------------------------------
// K4: LIF scan over T (sequential), one thread per chain (7168 chains).
// reset_{t+1} == spk_t (mem>1  <=>  mem-1>0, exact for f64 by Sterbenz).
// Double-buffered 16-deep register prefetch; spikes bit-packed per 32 steps.
// ---------------------------------------------------------------------------
__global__ __launch_bounds__(64) void k4_scan(
    const double* __restrict__ Ibuf, unsigned* __restrict__ spk)
{
    const int chain = blockIdx.x * 64 + threadIdx.x;
    const double* p = Ibuf + chain;

    double va[16], vb[16];
    #pragma unroll
    for (int u = 0; u < 16; ++u) va[u] = p[(size_t)u * CH];

    double mem = 0.0;
    int r = 0;
    unsigned bits = 0;

    for (int t0 = 0; t0 < TTT; t0 += 32) {
        #pragma unroll
        for (int u = 0; u < 16; ++u) vb[u] = p[(size_t)(t0 + 16 + u) * CH];
        #pragma unroll
        for (int u = 0; u < 16; ++u) {
            mem = 0.95 * mem + va[u] - (r ? 1.0 : 0.0);
            r = (mem - 1.0) > 0.0;
            bits |= (unsigned)r << u;
        }
        if (t0 + 32 < TTT) {
            #pragma unroll
            for (int u = 0; u < 16; ++u) va[u] = p[(size_t)(t0 + 32 + u) * CH];
        }
        #pragma unroll
        for (int u = 0; u < 16; ++u) {
            mem = 0.95 * mem + vb[u] - (r ? 1.0 : 0.0);
            r = (mem - 1.0) > 0.0;
            bits |= (unsigned)r << (16 + u);
        }
        spk[(size_t)(t0 >> 5) * CH + chain] = bits;   // coalesced u32 store
        bits = 0;
    }
}

// ---------------------------------------------------------------------------
// K5: unpack bits -> float out[b][c][t] (= out[chain][t]), coalesced writes
// ---------------------------------------------------------------------------
__global__ __launch_bounds__(256) void k5_unpack(
    const unsigned* __restrict__ spk, float* __restrict__ out)
{
    const int g = blockIdx.x * 256 + threadIdx.x;
    const int chain = g >> 11;        // / 2048
    const int t = g & 2047;
    unsigned bits = spk[(size_t)(t >> 5) * CH + chain];
    out[g] = ((bits >> (t & 31)) & 1u) ? 1.0f : 0.0f;
}

// ---------------------------------------------------------------------------
extern "C" void kernel_launch(void* const* d_in, const int* in_sizes, int n_in,
                              void* d_out, int out_size, void* d_ws, size_t ws_size,
                              hipStream_t stream)
{
    const float* x  = (const float*)d_in[0];   // (32,1,224,2048) f32
    const float* lw = (const float*)d_in[1];   // (1,224) f32
    float* out = (float*)d_out;                // (32,1,224,2048) f32

    // workspace layout (all 8B-aligned), total 188,481,536 bytes
    char* ws = (char*)d_ws;
    float*    xT    = (float*)(ws);                    //  58,720,256 B
    double*   wpart = (double*)(ws + 58720256);        //   3,670,016 B
    double*   kern  = (double*)(ws + 62390272);        //   6,815,744 B
    double*   Ibuf  = (double*)(ws + 69206016);        // 117,440,512 B
    unsigned* spk   = (unsigned*)(ws + 186646528);     //   1,835,008 B

    k1_transpose_dot<<<dim3(32, 7, 32), 256, 0, stream>>>(x, lw, xT, wpart);
    k2_kern<<<BT / 256, 256, 0, stream>>>(wpart, kern);
    k3_conv<<<16384, 256, 0, stream>>>(xT, kern, Ibuf);
    k4_scan<<<CH / 64, 64, 0, stream>>>(Ibuf, spk);
    k5_unpack<<<(BB * CCH * TTT) / 256, 256, 0, stream>>>(spk, out);
}

// Round 2
// 201.156 us; speedup vs baseline: 1.2232x; 1.2232x over previous
//
#include <hip/hip_runtime.h>
#include <math.h>

#define BB 32
#define CCH 224
#define TTT 2048
#define CH (BB*CCH)      // 7168 chains
#define TT 16            // t-tile per KA block
#define ROWP 244         // padded LDS row (floats): 244%32=20 -> conflict-free-ish, 976B = 16B-aligned

// ---------------------------------------------------------------------------
// KA: fused  [stage x tile] + [dot over C -> w -> Gaussian kern] + [13-tap conv]
// grid (T/TT=128, B=32), block 256.  Writes I in paired-f64 layout:
//   I2[(t>>1)*CH + chain] = double2{ I(t_even), I(t_odd) },  chain = b*224+c
// ---------------------------------------------------------------------------
__global__ __launch_bounds__(256) void ka_conv(
    const float* __restrict__ x, const float* __restrict__ lw,
    double2* __restrict__ I2)
{
    __shared__ __align__(16) float sh[TT][ROWP];   // sh[t][p] = x[b, p-6, t0+t]
    __shared__ double kd[TT][13];
    __shared__ float  lwsh[CCH];

    const int tid = threadIdx.x;
    const int b   = blockIdx.y;
    const int t0  = blockIdx.x * TT;

    // ---- Phase A: stage tile + halos + lw ----
    if (tid < CCH) lwsh[tid] = lw[tid];
    if (tid < TT * 12) {                 // zero halos: p in [0,6) and [230,236)
        int t = tid / 12, h = tid % 12;
        sh[t][h < 6 ? h : h + 224] = 0.0f;
    }
    #pragma unroll
    for (int it = 0; it < (CCH * TT) / 256; ++it) {
        int idx = it * 256 + tid;        // idx = c*16 + t
        int c = idx >> 4, t = idx & 15;
        sh[t][6 + c] = x[((size_t)(b * CCH + c) << 11) + t0 + t];
    }
    __syncthreads();

    // ---- Phase B: dot over C (wave 0), w -> kern via power recurrences ----
    if (tid < 64) {
        int t = tid & 15, m = tid >> 4;  // 4 partials of 56 channels each
        double acc = 0.0;
        for (int i = 0; i < 56; ++i)
            acc += (double)sh[t][6 + 56 * m + i] * (double)lwsh[56 * m + i];
        acc += __shfl_xor(acc, 16);
        acc += __shfl_xor(acc, 32);
        if (m == 0) {
            double w = 5.2 + acc * 9.6;                   // sigma_mean + dot*(SMAX-SMIN)
            w = fmin(fmax(w, 0.4), 10.0);
            double iw2 = 1.0 / (w * w);
            // norm = sum exp(-0.5*(r/w)^2), r=(i-64.5)*s, i=0..129  (odd m=2u+1 halves x2)
            const double s = 120.0 / 129.0;
            double G  = exp(-0.125 * s * s * iw2);        // G = exp(-0.5*(s/(2w))^2)
            double G2 = G * G, G4 = G2 * G2, G8 = G4 * G4;
            double term = G, cmul = G8, norm = G;         // term_u = G^{(2u+1)^2}
            for (int u = 1; u <= 64; ++u) { term *= cmul; cmul *= G8; norm += term; }
            norm *= 2.0;
            // taps: e[d] = exp(-0.5*d^2/w^2) = P^{d^2}
            double P = exp(-0.5 * iw2), P2 = P * P;
            double a = 1.0, bm = P, inv = 1.0 / norm;
            kd[t][6] = inv;
            for (int d = 1; d <= 6; ++d) {
                a *= bm; bm *= P2;
                double v = a * inv;
                kd[t][6 + d] = v; kd[t][6 - d] = v;
            }
        }
    }
    __syncthreads();

    // ---- Phase C: conv, thread = 8 channels x 1 t-pair ----
    const int j  = tid & 31;             // octet 0..27 (28*8 = 224 channels)
    const int pi = tid >> 5;             // pair 0..7 (TT=16 -> 8 pairs)
    if (j < 28) {
        const int te = 2 * pi, to = te + 1;
        double k0[13], k1[13];
        #pragma unroll
        for (int k = 0; k < 13; ++k) { k0[k] = kd[te][k]; k1[k] = kd[to][k]; }

        float w0[20], w1[20];
        #pragma unroll
        for (int e = 0; e < 5; ++e) {
            ((float4*)w0)[e] = ((const float4*)&sh[te][8 * j])[e];
            ((float4*)w1)[e] = ((const float4*)&sh[to][8 * j])[e];
        }

        double2* dst = I2 + (size_t)((t0 >> 1) + pi) * CH + b * CCH + 8 * j;
        #pragma unroll
        for (int m = 0; m < 8; ++m) {
            double a0 = 0.0, a1 = 0.0;
            #pragma unroll
            for (int k = 0; k < 13; ++k) {
                a0 = fma((double)w0[m + k], k0[k], a0);
                a1 = fma((double)w1[m + k], k1[k], a1);
            }
            double xv0 = (double)w0[m + 6], xv1 = (double)w1[m + 6];
            double d0 = xv0 - a0, d1 = xv1 - a1;
            dst[m] = make_double2(xv0 - (d0 > 0.0 ? d0 : 0.0),
                                  xv1 - (d1 > 0.0 ? d1 : 0.0));
        }
    }
}

// ---------------------------------------------------------------------------
// KB: LIF scan, one thread per chain; 64-step double-buffered batches of
// double2 loads (16B/lane, 32 loads = 32KB outstanding). Dual-fma + cndmask.
// ---------------------------------------------------------------------------
#define STEPS64(V)                                                        \
    {                                                                     \
        lo = 0u; hi = 0u;                                                 \
        _Pragma("unroll")                                                 \
        for (int u = 0; u < 32; ++u) {                                    \
            double a0 = V[u].x, c0 = a0 - 1.0;                            \
            double m1 = fma(0.95, mem, a0);                               \
            double m2 = fma(0.95, mem, c0);                               \
            mem = r ? m2 : m1;                                            \
            r = mem > 1.0;                                                \
            unsigned bit0 = r ? 1u : 0u;                                  \
            double a1 = V[u].y, c1 = a1 - 1.0;                            \
            m1 = fma(0.95, mem, a1);                                      \
            m2 = fma(0.95, mem, c1);                                      \
            mem = r ? m2 : m1;                                            \
            r = mem > 1.0;                                                \
            unsigned two = bit0 | ((r ? 1u : 0u) << 1);                   \
            if (u < 16) lo |= two << (2 * u); else hi |= two << (2 * u - 32); \
        }                                                                 \
    }

__global__ __launch_bounds__(64, 1) void kb_scan(
    const double2* __restrict__ I2, unsigned* __restrict__ spk)
{
    const int chain = blockIdx.x * 64 + threadIdx.x;
    const double2* p = I2 + chain;

    double2 A[32], Bv[32];
    #pragma unroll
    for (int u = 0; u < 32; ++u) A[u] = p[(size_t)u * CH];

    double mem = 0.0;
    bool r = false;
    unsigned lo, hi;

    #pragma unroll 1
    for (int t0 = 0; t0 < TTT; t0 += 128) {
        const int pb = t0 >> 1;
        #pragma unroll
        for (int u = 0; u < 32; ++u) Bv[u] = p[(size_t)(pb + 32 + u) * CH];

        STEPS64(A)
        spk[(size_t)((t0 >> 5) + 0) * CH + chain] = lo;
        spk[(size_t)((t0 >> 5) + 1) * CH + chain] = hi;

        if (t0 + 128 < TTT) {
            #pragma unroll
            for (int u = 0; u < 32; ++u) A[u] = p[(size_t)(pb + 64 + u) * CH];
        }

        STEPS64(Bv)
        spk[(size_t)((t0 >> 5) + 2) * CH + chain] = lo;
        spk[(size_t)((t0 >> 5) + 3) * CH + chain] = hi;
    }
}

// ---------------------------------------------------------------------------
// KC: unpack bits -> float4 out[b][c][t], fully coalesced 16B stores
// ---------------------------------------------------------------------------
__global__ __launch_bounds__(256) void kc_unpack(
    const unsigned* __restrict__ spk, float4* __restrict__ out)
{
    const int g = blockIdx.x * 256 + threadIdx.x;
    const int chain = g >> 9;            // 512 float4 per chain
    const int t4 = (g & 511) * 4;
    unsigned bits = spk[(size_t)(t4 >> 5) * CH + chain] >> (t4 & 31);
    out[g] = make_float4((bits & 1u) ? 1.0f : 0.0f,
                         (bits & 2u) ? 1.0f : 0.0f,
                         (bits & 4u) ? 1.0f : 0.0f,
                         (bits & 8u) ? 1.0f : 0.0f);
}

// ---------------------------------------------------------------------------
extern "C" void kernel_launch(void* const* d_in, const int* in_sizes, int n_in,
                              void* d_out, int out_size, void* d_ws, size_t ws_size,
                              hipStream_t stream)
{
    const float* x  = (const float*)d_in[0];   // (32,1,224,2048) f32
    const float* lw = (const float*)d_in[1];   // (1,224) f32
    float4* out = (float4*)d_out;

    char* ws = (char*)d_ws;
    double2*  I2  = (double2*)(ws);                 // 1024*7168*16 = 117,440,512 B
    unsigned* spk = (unsigned*)(ws + 117440512);    // 64*7168*4    =   1,835,008 B

    ka_conv<<<dim3(TTT / TT, BB), 256, 0, stream>>>(x, lw, I2);
    kb_scan<<<CH / 64, 64, 0, stream>>>(I2, spk);
    kc_unpack<<<(BB * CCH * TTT / 4) / 256, 256, 0, stream>>>(spk, out);
}

// Round 3
// 153.068 us; speedup vs baseline: 1.6074x; 1.3142x over previous
//
#include <hip/hip_runtime.h>
#include <math.h>

#define BB 32
#define CCH 224
#define TTT 2048
#define TPB 64             // t per tile in kf
#define NT  (TTT/TPB)      // 32 tiles
#define CG  28             // chains (channels) per kf block
#define NCG (CCH/CG)       // 8
#define ROWS 40            // CG + 12 halo rows
#define XROW 68            // floats per xs row (64 + 4 pad, 16B-aligned)
#define IROW 29            // f64 per I row (28 + 1 pad)

// ---------------------------------------------------------------------------
// kw: per (b,t): f64 dot over C -> w -> 7 symmetric Gaussian taps (f64)
// grid (8, 32) x 256. Reads x fully coalesced (256B/wave-instr per channel).
// ---------------------------------------------------------------------------
__global__ __launch_bounds__(256) void kw(
    const float* __restrict__ x, const float* __restrict__ lw,
    double* __restrict__ kernG)
{
    const int b = blockIdx.y;
    const int t = blockIdx.x * 256 + threadIdx.x;
    const float* xb = x + (((size_t)b * CCH) << 11) + t;

    double p0 = 0, p1 = 0, p2 = 0, p3 = 0;
    #pragma unroll 8
    for (int i = 0; i < 56; ++i) {
        p0 += (double)xb[(size_t)i << 11]         * (double)lw[i];
        p1 += (double)xb[(size_t)(i + 56) << 11]  * (double)lw[i + 56];
        p2 += (double)xb[(size_t)(i + 112) << 11] * (double)lw[i + 112];
        p3 += (double)xb[(size_t)(i + 168) << 11] * (double)lw[i + 168];
    }
    double acc = (p0 + p1) + (p2 + p3);

    double w = 5.2 + acc * 9.6;
    w = fmin(fmax(w, 0.4), 10.0);
    double iw2 = 1.0 / (w * w);

    // norm over linspace(-60,60,130): exactly symmetric -> 2x half-sum,
    // terms G^{(2u+1)^2} via power recurrence (2 exps total)
    const double s = 120.0 / 129.0;
    double G  = exp(-0.125 * s * s * iw2);
    double G2 = G * G, G4 = G2 * G2, G8 = G4 * G4;
    double term = G, cmul = G8, norm = G;
    for (int u = 1; u <= 64; ++u) { term *= cmul; cmul *= G8; norm += term; }
    norm *= 2.0;

    double P = exp(-0.5 * iw2), P2 = P * P;
    double a = 1.0, bm = P, inv = 1.0 / norm;
    double* kr = kernG + (size_t)(b * TTT + t) * 7;
    kr[0] = inv;                      // center tap
    #pragma unroll
    for (int d = 1; d <= 6; ++d) {
        a *= bm; bm *= P2;
        kr[d] = a * inv;              // tap at distance d (symmetric)
    }
}

// ---------------------------------------------------------------------------
// kf: fused conv + LIF scan + spike output. grid (8, 32) x 192 threads.
// wave0 = scan (28 chains); waves 1-2 = conv/stage/out-write.
// Pipeline (1 barrier per phase), verified slot-by-slot:
//   phase k: conv(k)->Is[k&1]; stage(k+1)->xs/kd[(k+1)&1]; scan(k-1) reads
//   Is[(k-1)&1] -> bitsb[(k-1)&1]; out-write(k-2) reads bitsb[k&1].
// ---------------------------------------------------------------------------
__global__ __launch_bounds__(192) void kf(
    const float* __restrict__ x, const double* __restrict__ kernG,
    float* __restrict__ out)
{
    __shared__ __align__(16) float xs[2][ROWS][XROW];      // 21760 B
    __shared__ double kd[2][TPB][7];                       //  7168 B
    __shared__ double Is[2][TPB][IROW];                    // 29696 B
    __shared__ unsigned long long bitsb[2][CG];            //   448 B

    const int b   = blockIdx.y;
    const int cgi = blockIdx.x;
    const int c0  = cgi * CG;
    const int tid = threadIdx.x;
    const int ctid = tid - 64;

    const float*  xbase = x + (((size_t)(b * CCH)) << 11);
    const double* kbase = kernG + (size_t)(b * TTT) * 7;
    float* obase = out + (((size_t)(b * CCH + c0)) << 11);

    double mem = 0.0;   // scan state (wave0 lanes)
    bool   r   = false;

    // ---- prologue: stage tile 0 ----
    if (tid >= 64) {
        #pragma unroll
        for (int i2 = 0; i2 < 5; ++i2) {
            int e = ctid + i2 * 128;
            int rr = e >> 4, q = e & 15;
            int cr = c0 - 6 + rr;
            float4 v = make_float4(0.f, 0.f, 0.f, 0.f);
            if (cr >= 0 && cr < CCH)
                v = *(const float4*)(xbase + ((size_t)cr << 11) + 4 * q);
            *(float4*)&xs[0][rr][4 * q] = v;
        }
        if (ctid < TPB) {
            const double* kp = kbase + (size_t)ctid * 7;
            #pragma unroll
            for (int i2 = 0; i2 < 7; ++i2) kd[0][ctid][i2] = kp[i2];
        }
    }
    __syncthreads();

    for (int k = 0; k <= NT + 1; ++k) {
        if (tid >= 64) {
            const int buf = k & 1, nbuf = (k + 1) & 1;
            // 1) issue global loads for tile k+1 (latency hidden under conv)
            float4 rv[5]; double kv[7];
            const bool st = (k + 1 <= NT - 1);
            if (st) {
                const int gt0 = (k + 1) * TPB;
                #pragma unroll
                for (int i2 = 0; i2 < 5; ++i2) {
                    int e = ctid + i2 * 128;
                    int rr = e >> 4, q = e & 15;
                    int cr = c0 - 6 + rr;
                    rv[i2] = make_float4(0.f, 0.f, 0.f, 0.f);
                    if (cr >= 0 && cr < CCH)
                        rv[i2] = *(const float4*)(xbase + ((size_t)cr << 11) + gt0 + 4 * q);
                }
                if (ctid < TPB) {
                    const double* kp = kbase + (size_t)(gt0 + ctid) * 7;
                    #pragma unroll
                    for (int i2 = 0; i2 < 7; ++i2) kv[i2] = kp[i2];
                }
            }
            // 2) conv(k): thread = (t, half) -> 14 channels, sliding 13-row ring
            if (k <= NT - 1) {
                const int t  = ctid & 63;
                const int ch = ctid >> 6;       // 0/1
                const int cb = 14 * ch;
                double kk7[7];
                #pragma unroll
                for (int i2 = 0; i2 < 7; ++i2) kk7[i2] = kd[buf][t][i2];
                float xv[13];
                #pragma unroll
                for (int i2 = 0; i2 < 13; ++i2) xv[i2] = xs[buf][cb + i2][t];
                #pragma unroll
                for (int c = 0; c < 14; ++c) {
                    double acc = 0.0;
                    #pragma unroll
                    for (int kk2 = 0; kk2 < 13; ++kk2) {
                        int d = kk2 < 6 ? 6 - kk2 : kk2 - 6;
                        acc = fma((double)xv[(c + kk2) % 13], kk7[d], acc);
                    }
                    double xvv = (double)xv[(c + 6) % 13];
                    double dd  = xvv - acc;
                    Is[buf][t][cb + c] = xvv - (dd > 0.0 ? dd : 0.0);
                    if (c < 13) xv[c % 13] = xs[buf][cb + c + 13][t];
                }
            }
            // 3) out-write(k-2): coalesced float4 spike stores
            if (k >= 2) {
                const int j = k - 2, jb = j & 1;
                const int t0o = j * TPB;
                #pragma unroll
                for (int i2 = 0; i2 < 4; ++i2) {
                    int e = ctid + i2 * 128;
                    if (e < 448) {
                        int c = e >> 4, q = e & 15;
                        unsigned long long bits = bitsb[jb][c] >> (4 * q);
                        float4 v;
                        v.x = (bits & 1ull) ? 1.0f : 0.0f;
                        v.y = (bits & 2ull) ? 1.0f : 0.0f;
                        v.z = (bits & 4ull) ? 1.0f : 0.0f;
                        v.w = (bits & 8ull) ? 1.0f : 0.0f;
                        *(float4*)(obase + ((size_t)c << 11) + t0o + 4 * q) = v;
                    }
                }
            }
            // 4) drain staged regs -> LDS (next buffers)
            if (st) {
                #pragma unroll
                for (int i2 = 0; i2 < 5; ++i2) {
                    int e = ctid + i2 * 128;
                    int rr = e >> 4, q = e & 15;
                    *(float4*)&xs[nbuf][rr][4 * q] = rv[i2];
                }
                if (ctid < TPB) {
                    #pragma unroll
                    for (int i2 = 0; i2 < 7; ++i2) kd[nbuf][ctid][i2] = kv[i2];
                }
            }
        } else {
            // scan(k-1): 8-deep double-buffered prefetch, ~10cyc/step chain
            if (k >= 1 && k <= NT) {
                const int p = (k - 1) & 1;
                const int c = tid;
                if (c < CG) {
                    unsigned long long bits = 0ull;
                    double va[8], vb[8];
                    #pragma unroll
                    for (int j2 = 0; j2 < 8; ++j2) va[j2] = Is[p][j2][c];
                    #pragma unroll
                    for (int g = 0; g < 64; g += 16) {
                        #pragma unroll
                        for (int j2 = 0; j2 < 8; ++j2) vb[j2] = Is[p][g + 8 + j2][c];
                        #pragma unroll
                        for (int j2 = 0; j2 < 8; ++j2) {
                            double a2 = va[j2];
                            double cm = a2 - 1.0;
                            double m1 = fma(0.95, mem, a2);
                            double m2 = fma(0.95, mem, cm);
                            mem = r ? m2 : m1;
                            r = mem > 1.0;
                            bits |= (unsigned long long)(r ? 1 : 0) << (g + j2);
                        }
                        if (g + 16 < 64) {
                            #pragma unroll
                            for (int j2 = 0; j2 < 8; ++j2) va[j2] = Is[p][g + 16 + j2][c];
                        }
                        #pragma unroll
                        for (int j2 = 0; j2 < 8; ++j2) {
                            double a2 = vb[j2];
                            double cm = a2 - 1.0;
                            double m1 = fma(0.95, mem, a2);
                            double m2 = fma(0.95, mem, cm);
                            mem = r ? m2 : m1;
                            r = mem > 1.0;
                            bits |= (unsigned long long)(r ? 1 : 0) << (g + 8 + j2);
                        }
                    }
                    bitsb[p][c] = bits;
                }
            }
        }
        __syncthreads();
    }
}

// ---------------------------------------------------------------------------
extern "C" void kernel_launch(void* const* d_in, const int* in_sizes, int n_in,
                              void* d_out, int out_size, void* d_ws, size_t ws_size,
                              hipStream_t stream)
{
    const float* x  = (const float*)d_in[0];   // (32,1,224,2048) f32
    const float* lw = (const float*)d_in[1];   // (1,224) f32
    float* out = (float*)d_out;                // (32,1,224,2048) f32

    double* kernG = (double*)d_ws;             // 65536 * 7 * 8 = 3,670,016 B

    kw<<<dim3(TTT / 256, BB), 256, 0, stream>>>(x, lw, kernG);
    kf<<<dim3(NCG, BB), 192, 0, stream>>>(x, kernG, out);
}